// Round 6
// baseline (108.882 us; speedup 1.0000x reference)
//
#include <hip/hip_runtime.h>
#include <hip/hip_fp16.h>

// Fast discrete Radon transform (exact, wrap-around shears), radix-16,
// single fused kernel with grid barriers, fp16 intermediates.
//   case A (m<512):   R_m[t]  = sum_y img[(t - m*y) & 511, y]
//   case B (m>=512):  R'_a[t] = sum_x img[x, (t - 2a*x) & 511], a = m-512
// out = R * (1/sqrt(512)), imag exactly 0.
//
// D_q[c][w][x] = sum_{u<q} A'[u*h+w][(x - c*u*h) & 511],  h = 512/q
// D_{16q}[C][w][x] = sum_{b<16} D_q[C mod q][w + b*H][(x - C*b*H) & 511]
// Stages: 1 ->(init, radix-2) 2 ->(radix-16) 32 ->(radix-16, fused out) 512.

#define NN 512
#define MU 768
#define MASK 511
#define SCALE 0.04419417382415922f  // 1/sqrt(512)
#define NB 768

typedef float v4f __attribute__((ext_vector_type(4)));  // nontemporal-store-able

union H8 { float4 f4; __half2 h2[4]; };
union H4 { float2 f2; __half2 h2[2]; };

// Monotonic grid barrier: every block adds 1, waits for cnt >= target.
// Requires all NB blocks co-resident (launch_bounds(512,6) -> 3 blocks/CU x
// 256 CUs = 768 = NB; LDS 33.3KB*3 <= 160KB; verified at launch time via
// hipOccupancyMaxActiveBlocksPerMultiprocessor, else fallback path).
__device__ __forceinline__ void gridbar(unsigned* cnt, unsigned target) {
  __syncthreads();
  if (threadIdx.x == 0) {
    __threadfence();                 // flush this block's writes (device scope)
    atomicAdd(cnt, 1u);              // device-scope RMW
    while (__atomic_load_n(cnt, __ATOMIC_ACQUIRE) < target)
      __builtin_amdgcn_s_sleep(8);
    __threadfence();                 // invalidate stale L1 before reading peers' data
  }
  __syncthreads();
}

__global__ __launch_bounds__(512, 6) void drt_fused(
    const float* __restrict__ img, float2* __restrict__ out,
    __half* __restrict__ A0, __half* __restrict__ B0,
    __half* __restrict__ A1, __half* __restrict__ B1,
    unsigned* __restrict__ bar) {
  __shared__ float LDS[8320];  // init: 2 x 64x65 fp32; passes: 16x512 fp32
  const int bid = blockIdx.x;
  const int t = threadIdx.x;

  // ================= phase 0: init (radix-2), fp16 out ====================
  if (bid < 512) {
    // case A: transpose + radix-2.  unit = (b, 64x64 tile)
    const int b = bid >> 5, tile = bid & 31;
    const int xt = tile & 7, wt = tile >> 3;
    const int x0 = xt * 64, w0 = wt * 64, x3 = ((xt + 4) & 7) * 64;
    const float* src = img + (size_t)b * NN * NN;
    float* TA = LDS;          // [64][65]
    float* TB = LDS + 4160;   // [64][65]
    for (int idx = t; idx < 4096; idx += 512) {
      int rr = idx >> 6, cc = idx & 63;
      TA[rr * 65 + cc] = src[(x0 + rr) * NN + w0 + cc];
      TB[rr * 65 + cc] = src[(x0 + rr) * NN + w0 + 256 + cc];
    }
    __syncthreads();
    __half2* d = (__half2*)A0 + (size_t)b * 512 * 256;
    for (int idx = t; idx < 2048; idx += 512) {
      int wl = idx >> 5, xp = idx & 31;
      float a0 = TA[(2 * xp) * 65 + wl] + TB[(2 * xp) * 65 + wl];
      float a1 = TA[(2 * xp + 1) * 65 + wl] + TB[(2 * xp + 1) * 65 + wl];
      d[(w0 + wl) * 256 + (x0 >> 1) + xp] = __float22half2_rn(make_float2(a0, a1));
    }
    __syncthreads();
    for (int idx = t; idx < 4096; idx += 512) {
      int rr = idx >> 6, cc = idx & 63;
      TB[rr * 65 + cc] = src[(x3 + rr) * NN + w0 + 256 + cc];
    }
    __syncthreads();
    for (int idx = t; idx < 2048; idx += 512) {
      int wl = idx >> 5, xp = idx & 31;
      float a0 = TA[(2 * xp) * 65 + wl] + TB[(2 * xp) * 65 + wl];
      float a1 = TA[(2 * xp + 1) * 65 + wl] + TB[(2 * xp + 1) * 65 + wl];
      d[(256 + w0 + wl) * 256 + (x0 >> 1) + xp] = __float22half2_rn(make_float2(a0, a1));
    }
  } else {
    // case B: radix-2, no transpose. 16 rows per unit.
    const int v = bid - 512, b = v >> 4, unit = v & 15;
    const int w0 = unit * 16;
    const float2* s2 = (const float2*)(img + (size_t)b * NN * NN);
    __half2* d = (__half2*)B0 + (size_t)b * 256 * 256;
    for (int it = 0; it < 8; ++it) {
      int flat = it * 512 + t;
      int row = w0 + (flat >> 8), cp = flat & 255;
      float2 u = s2[row * 256 + cp], vv = s2[(row + 256) * 256 + cp];
      d[row * 256 + cp] = __float22half2_rn(make_float2(u.x + vv.x, u.y + vv.y));
    }
  }

  gridbar(bar, NB);

  // ================= phase 1: stage 2 -> 32 (H=16) ========================
  {
    const int b = bid / 48, bx = bid - b * 48;
    const bool isB = bx >= 32;
    const int c = isB ? 0 : (bx >> 4);
    const int w = isB ? (bx - 32) : (bx & 15);
    const __half* in = isB ? (B0 + (size_t)b * 256 * NN) : (A0 + (size_t)b * 512 * NN);
    const int pbase = c * 256 + w;
    float* L = LDS;
    const float4* s4 = (const float4*)in;
    for (int it = 0; it < 2; ++it) {
      int flat = it * 512 + t;  // 1024 chunks of 8 halves
      int lrow = flat >> 6, ch = flat & 63;
      H8 u; u.f4 = s4[(size_t)(pbase + 16 * lrow) * 64 + ch];
      float2 p0 = __half22float2(u.h2[0]), p1 = __half22float2(u.h2[1]);
      float2 p2 = __half22float2(u.h2[2]), p3 = __half22float2(u.h2[3]);
      float4* l4 = (float4*)&L[lrow * 512 + ch * 8];
      l4[0] = make_float4(p0.x, p0.y, p1.x, p1.y);
      l4[1] = make_float4(p2.x, p2.y, p3.x, p3.y);
    }
    __syncthreads();
    const int g = t >> 7;
    const int x4 = (t & 127) * 4;
    __half* outA = A1 + (size_t)b * 512 * NN;
    __half* outB = B1 + (size_t)b * 256 * NN;
    for (int jj = 0; jj < 4; ++jj) {
      const int j = jj * 4 + g;
      const int C = isB ? (2 * j) : (c + 2 * j);
      float4 acc = {0.f, 0.f, 0.f, 0.f};
#pragma unroll
      for (int bb = 0; bb < 16; ++bb) {
        int base = (x4 - C * bb * 16) & MASK;  // %4==0: aligned, no wrap split
        float4 v = *(const float4*)&L[bb * 512 + base];
        acc.x += v.x; acc.y += v.y; acc.z += v.z; acc.w += v.w;
      }
      const int orow = isB ? (j * 16 + w) : (C * 16 + w);
      H4 h;
      h.h2[0] = __float22half2_rn(make_float2(acc.x, acc.y));
      h.h2[1] = __float22half2_rn(make_float2(acc.z, acc.w));
      float2* op = (float2*)(isB ? outB : outA);
      op[orow * 128 + (x4 >> 2)] = h.f2;
    }
  }

  gridbar(bar, 2 * NB);

  // ====== phase 2: stage 32 -> 512 (H=1), rotated staging, fused out ======
  {
    const int b = bid / 48, bx = bid - b * 48;
    const bool isB = bx >= 32;
    const int c = isB ? 2 * (bx - 32) : bx;  // stage-32 class
    const __half* in = isB ? (B1 + (size_t)b * 256 * NN + (size_t)(bx - 32) * 16 * NN)
                           : (A1 + (size_t)b * 512 * NN + (size_t)c * 16 * NN);
    float* L = LDS;
    const __half2* i2 = (const __half2*)in;
    for (int it = 0; it < 8; ++it) {
      int flat = it * 512 + t;
      int bb = flat >> 8, p = flat & 255;
      float2 f = __half22float2(i2[bb * 256 + p]);
      int y0 = (2 * p + c * bb) & MASK;     // row bb rotated by c*bb
      L[bb * 512 + y0] = f.x;
      L[bb * 512 + ((y0 + 1) & MASK)] = f.y;
    }
    __syncthreads();
    const int g = t >> 7;
    const int xq = (t & 127) << 2;
    float4 acc[4];
#pragma unroll
    for (int jj = 0; jj < 4; ++jj) acc[jj] = {0.f, 0.f, 0.f, 0.f};
#pragma unroll
    for (int bb = 0; bb < 16; ++bb) {
      const float* row = L + bb * 512;
      int base = (xq - 128 * g * bb) & MASK;  // shift 32*j*bb, j=4g
      const int step = (32 * bb) & MASK;
#pragma unroll
      for (int jj = 0; jj < 4; ++jj) {
        float4 v = *(const float4*)&row[base];  // aligned, wrap-free
        acc[jj].x += v.x; acc[jj].y += v.y; acc[jj].z += v.z; acc[jj].w += v.w;
        base = (base - step) & MASK;
      }
    }
#pragma unroll
    for (int jj = 0; jj < 4; ++jj) {
      const int j = 4 * g + jj;
      const int m = isB ? (512 + (bx - 32) + 16 * j) : (c + 32 * j);
      v4f o1 = {acc[jj].x * SCALE, 0.f, acc[jj].y * SCALE, 0.f};
      v4f o2 = {acc[jj].z * SCALE, 0.f, acc[jj].w * SCALE, 0.f};
      v4f* op = (v4f*)(out + ((size_t)b * MU + m) * NN + xq);
      __builtin_nontemporal_store(o1, op);      // out is never re-read
      __builtin_nontemporal_store(o2, op + 1);
    }
  }
}

// ============ fallback path: 3 separate fp32 kernels (round-3/4) ==========
__global__ __launch_bounds__(256) void k_init(const float* __restrict__ img,
                                              float* __restrict__ A0,
                                              float* __restrict__ B0) {
  const int bx = blockIdx.x, b = blockIdx.y;
  const float* src = img + (size_t)b * NN * NN;
  if (bx < 32) {
    __shared__ float T1[64][65], T2[64][65], T3[64][65];
    const int xt = bx & 7, wt = bx >> 3;
    const int x0 = xt * 64, w0 = wt * 64, x3 = ((xt + 4) & 7) * 64;
    for (int idx = threadIdx.x; idx < 4096; idx += 256) {
      int rr = idx >> 6, cc = idx & 63;
      T1[rr][cc] = src[(x0 + rr) * NN + w0 + cc];
      T2[rr][cc] = src[(x0 + rr) * NN + w0 + 256 + cc];
      T3[rr][cc] = src[(x3 + rr) * NN + w0 + 256 + cc];
    }
    __syncthreads();
    float* dst = A0 + (size_t)b * (512 * NN);
    for (int idx = threadIdx.x; idx < 4096; idx += 256) {
      int wl = idx >> 6, xl = idx & 63;
      float t1 = T1[xl][wl];
      dst[(size_t)(w0 + wl) * NN + x0 + xl]       = t1 + T2[xl][wl];
      dst[(size_t)(256 + w0 + wl) * NN + x0 + xl] = t1 + T3[xl][wl];
    }
  } else {
    const int w0 = (bx - 32) * 32;
    const float4* s4 = (const float4*)src;
    float4* d4 = (float4*)(B0 + (size_t)b * (256 * NN));
    for (int it = 0; it < 16; ++it) {
      int flat = it * 256 + threadIdx.x;
      int row = w0 + (flat >> 7), col = flat & 127;
      float4 u = s4[row * 128 + col], v = s4[(row + 256) * 128 + col];
      u.x += v.x; u.y += v.y; u.z += v.z; u.w += v.w;
      d4[row * 128 + col] = u;
    }
  }
}

__global__ __launch_bounds__(512) void k_pass1(const float* __restrict__ A0,
                                               const float* __restrict__ B0,
                                               float* __restrict__ A1,
                                               float* __restrict__ B1) {
  __shared__ float L[16 * 512];
  const int bx = blockIdx.x, b = blockIdx.y;
  const int t = threadIdx.x;
  const bool isB = bx >= 32;
  const int c = isB ? 0 : (bx >> 4);
  const int w = isB ? (bx - 32) : (bx & 15);
  const float* in = isB ? (B0 + (size_t)b * 256 * NN) : (A0 + (size_t)b * 512 * NN);
  {
    const float4* s4 = (const float4*)in;
    float4* l4 = (float4*)L;
    const int pbase = c * 256 + w;
    for (int it = 0; it < 4; ++it) {
      int flat = it * 512 + t;
      int lrow = flat >> 7, col = flat & 127;
      l4[lrow * 128 + col] = s4[(pbase + 16 * lrow) * 128 + col];
    }
  }
  __syncthreads();
  const int g = t >> 7;
  const int x4 = (t & 127) * 4;
  float* outA = A1 + (size_t)b * 512 * NN;
  float* outB = B1 + (size_t)b * 256 * NN;
  for (int jj = 0; jj < 4; ++jj) {
    const int j = jj * 4 + g;
    const int C = isB ? (2 * j) : (c + 2 * j);
    float4 acc = {0.f, 0.f, 0.f, 0.f};
#pragma unroll
    for (int bb = 0; bb < 16; ++bb) {
      int base = (x4 - C * bb * 16) & MASK;
      float4 v = *(const float4*)&L[bb * 512 + base];
      acc.x += v.x; acc.y += v.y; acc.z += v.z; acc.w += v.w;
    }
    const int orow = isB ? (j * 16 + w) : (C * 16 + w);
    float* op = isB ? outB : outA;
    *(float4*)&op[(size_t)orow * NN + x4] = acc;
  }
}

__global__ __launch_bounds__(512) void k_pass2(const float* __restrict__ A1,
                                               const float* __restrict__ B1,
                                               float2* __restrict__ out) {
  __shared__ float L[16 * 512];
  const int bx = blockIdx.x, b = blockIdx.y;
  const int t = threadIdx.x;
  const bool isB = bx >= 32;
  const int c = isB ? 2 * (bx - 32) : bx;
  const float* in = isB ? (B1 + (size_t)b * 256 * NN + (size_t)(bx - 32) * 16 * NN)
                        : (A1 + (size_t)b * 512 * NN + (size_t)c * 16 * NN);
#pragma unroll
  for (int bb = 0; bb < 16; ++bb) {
    float v = in[bb * 512 + t];
    L[bb * 512 + ((t + c * bb) & MASK)] = v;
  }
  __syncthreads();
  const int g = t >> 7;
  const int xq = (t & 127) << 2;
  float4 acc[4];
#pragma unroll
  for (int jj = 0; jj < 4; ++jj) acc[jj] = {0.f, 0.f, 0.f, 0.f};
#pragma unroll
  for (int bb = 0; bb < 16; ++bb) {
    const float* row = L + bb * 512;
    int base = (xq - 128 * g * bb) & MASK;
    const int step = (32 * bb) & MASK;
#pragma unroll
    for (int jj = 0; jj < 4; ++jj) {
      float4 v = *(const float4*)&row[base];
      acc[jj].x += v.x; acc[jj].y += v.y; acc[jj].z += v.z; acc[jj].w += v.w;
      base = (base - step) & MASK;
    }
  }
#pragma unroll
  for (int jj = 0; jj < 4; ++jj) {
    const int j = 4 * g + jj;
    const int m = isB ? (512 + (bx - 32) + 16 * j) : (c + 32 * j);
    float2* op = out + ((size_t)b * MU + m) * NN + xq;
    float4 a = acc[jj];
    op[0] = {a.x * SCALE, 0.f};
    op[1] = {a.y * SCALE, 0.f};
    op[2] = {a.z * SCALE, 0.f};
    op[3] = {a.w * SCALE, 0.f};
  }
}

extern "C" void kernel_launch(void* const* d_in, const int* in_sizes, int n_in,
                              void* d_out, int out_size, void* d_ws, size_t ws_size,
                              hipStream_t stream) {
  const float* img = (const float*)d_in[0];

  int maxb = 0;
  (void)hipOccupancyMaxActiveBlocksPerMultiprocessor(&maxb, (const void*)drt_fused,
                                                     512, 0);
  const bool can_fuse = (maxb >= 3) && (ws_size >= (size_t)25165832);

  if (can_fuse) {
    char* W = (char*)d_ws;
    __half* A0 = (__half*)(W);              // 16 x 512 x 512 fp16
    __half* A1 = (__half*)(W + 8388608);    // 16 x 512 x 512 fp16
    __half* B0 = (__half*)(W + 16777216);   // 16 x 256 x 512 fp16
    __half* B1 = (__half*)(W + 20971520);   // 16 x 256 x 512 fp16
    unsigned* bar = (unsigned*)(W + 25165824);
    (void)hipMemsetAsync(bar, 0, 8, stream);  // graph-capturable memset node
    drt_fused<<<dim3(NB), dim3(512), 0, stream>>>(img, (float2*)d_out,
                                                  A0, B0, A1, B1, bar);
  } else if (ws_size >= (size_t)51 * 1024 * 1024) {
    float* W  = (float*)d_ws;
    float* A0 = W;
    float* A1 = W + 4194304;
    float* B0 = W + 8388608;
    float* B1 = W + 10485760;
    k_init <<<dim3(40, 16), dim3(256), 0, stream>>>(img, A0, B0);
    k_pass1<<<dim3(48, 16), dim3(512), 0, stream>>>(A0, B0, A1, B1);
    k_pass2<<<dim3(48, 16), dim3(512), 0, stream>>>(A1, B1, (float2*)d_out);
  }
}

// Round 7
// 105.161 us; speedup vs baseline: 1.0354x; 1.0354x over previous
//
#include <hip/hip_runtime.h>
#include <hip/hip_fp16.h>

// Fast discrete Radon transform (exact, wrap-around shears), radix-16,
// single fused kernel, per-batch pipelined barriers, fp16 intermediates.
//   case A (m<512):   R_m[t]  = sum_y img[(t - m*y) & 511, y]
//   case B (m>=512):  R'_a[t] = sum_x img[x, (t - 2a*x) & 511], a = m-512
// out = R * (1/sqrt(512)), imag exactly 0.
//
// D_q[c][w][x] = sum_{u<q} A'[u*h+w][(x - c*u*h) & 511],  h = 512/q
// D_{16q}[C][w][x] = sum_{b<16} D_q[C mod q][w + b*H][(x - C*b*H) & 511]
// Stages: 1 ->(init, radix-2) 2 ->(radix-16) 32 ->(radix-16, fused out) 512.
//
// Dependencies never cross batches, so barriers are per-batch monotonic
// counters (target 48 = blocks per batch per phase): a block signals the
// batch it produced, waits only on the batch it consumes. Batches pipeline
// through phases instead of convoying the whole grid.

#define NN 512
#define MU 768
#define MASK 511
#define SCALE 0.04419417382415922f  // 1/sqrt(512)
#define NB 768

typedef float v4f __attribute__((ext_vector_type(4)));  // nontemporal-store-able

union H8 { float4 f4; __half2 h2[4]; };
union H4 { float2 f2; __half2 h2[2]; };

// Producer side: flush writes, bump this batch's counter (device scope).
__device__ __forceinline__ void bar_signal(unsigned* cnt) {
  __syncthreads();
  if (threadIdx.x == 0) {
    __threadfence();
    atomicAdd(cnt, 1u);
  }
}
// Consumer side: spin until the consumed batch's 48 producers arrived.
// Deadlock-free: every block signals before it waits, all blocks co-resident.
__device__ __forceinline__ void bar_wait(unsigned* cnt) {
  if (threadIdx.x == 0) {
    while (__atomic_load_n(cnt, __ATOMIC_ACQUIRE) < 48u)
      __builtin_amdgcn_s_sleep(8);
    __threadfence();   // invalidate stale L1/L2-cached lines before reading
  }
  __syncthreads();
}

__global__ __launch_bounds__(512, 6) void drt_fused(
    const float* __restrict__ img, float2* __restrict__ out,
    __half* __restrict__ A0, __half* __restrict__ B0,
    __half* __restrict__ A1, __half* __restrict__ B1,
    unsigned* __restrict__ bar) {
  __shared__ float LDS[8320];  // init: 2 x 64x65 fp32; passes: 16x512 fp32
  const int bid = blockIdx.x;
  const int t = threadIdx.x;

  // ================= phase 0: init (radix-2), fp16 out ====================
  int p0b;  // batch this block produces in phase 0
  if (bid < 512) {
    // case A: transpose + radix-2.  unit = (b, 64x64 tile)
    const int b = bid >> 5, tile = bid & 31;
    p0b = b;
    const int xt = tile & 7, wt = tile >> 3;
    const int x0 = xt * 64, w0 = wt * 64, x3 = ((xt + 4) & 7) * 64;
    const float* src = img + (size_t)b * NN * NN;
    float* TA = LDS;          // [64][65]
    float* TB = LDS + 4160;   // [64][65]
    for (int idx = t; idx < 4096; idx += 512) {
      int rr = idx >> 6, cc = idx & 63;
      TA[rr * 65 + cc] = src[(x0 + rr) * NN + w0 + cc];
      TB[rr * 65 + cc] = src[(x0 + rr) * NN + w0 + 256 + cc];
    }
    __syncthreads();
    __half2* d = (__half2*)A0 + (size_t)b * 512 * 256;
    for (int idx = t; idx < 2048; idx += 512) {
      int wl = idx >> 5, xp = idx & 31;
      float a0 = TA[(2 * xp) * 65 + wl] + TB[(2 * xp) * 65 + wl];
      float a1 = TA[(2 * xp + 1) * 65 + wl] + TB[(2 * xp + 1) * 65 + wl];
      d[(w0 + wl) * 256 + (x0 >> 1) + xp] = __float22half2_rn(make_float2(a0, a1));
    }
    __syncthreads();
    for (int idx = t; idx < 4096; idx += 512) {
      int rr = idx >> 6, cc = idx & 63;
      TB[rr * 65 + cc] = src[(x3 + rr) * NN + w0 + 256 + cc];
    }
    __syncthreads();
    for (int idx = t; idx < 2048; idx += 512) {
      int wl = idx >> 5, xp = idx & 31;
      float a0 = TA[(2 * xp) * 65 + wl] + TB[(2 * xp) * 65 + wl];
      float a1 = TA[(2 * xp + 1) * 65 + wl] + TB[(2 * xp + 1) * 65 + wl];
      d[(256 + w0 + wl) * 256 + (x0 >> 1) + xp] = __float22half2_rn(make_float2(a0, a1));
    }
  } else {
    // case B: radix-2, no transpose. 16 rows per unit.
    const int v = bid - 512, b = v >> 4, unit = v & 15;
    p0b = b;
    const int w0 = unit * 16;
    const float2* s2 = (const float2*)(img + (size_t)b * NN * NN);
    __half2* d = (__half2*)B0 + (size_t)b * 256 * 256;
    for (int it = 0; it < 8; ++it) {
      int flat = it * 512 + t;
      int row = w0 + (flat >> 8), cp = flat & 255;
      float2 u = s2[row * 256 + cp], vv = s2[(row + 256) * 256 + cp];
      d[row * 256 + cp] = __float22half2_rn(make_float2(u.x + vv.x, u.y + vv.y));
    }
  }

  const int b = bid / 48, bx = bid - b * 48;  // phase-1/2 assignment
  bar_signal(&bar[p0b]);
  bar_wait(&bar[b]);

  // ================= phase 1: stage 2 -> 32 (H=16) ========================
  {
    const bool isB = bx >= 32;
    const int c = isB ? 0 : (bx >> 4);
    const int w = isB ? (bx - 32) : (bx & 15);
    const __half* in = isB ? (B0 + (size_t)b * 256 * NN) : (A0 + (size_t)b * 512 * NN);
    const int pbase = c * 256 + w;
    float* L = LDS;
    const float4* s4 = (const float4*)in;
    for (int it = 0; it < 2; ++it) {
      int flat = it * 512 + t;  // 1024 chunks of 8 halves
      int lrow = flat >> 6, ch = flat & 63;
      H8 u; u.f4 = s4[(size_t)(pbase + 16 * lrow) * 64 + ch];
      float2 p0 = __half22float2(u.h2[0]), p1 = __half22float2(u.h2[1]);
      float2 p2 = __half22float2(u.h2[2]), p3 = __half22float2(u.h2[3]);
      float4* l4 = (float4*)&L[lrow * 512 + ch * 8];
      l4[0] = make_float4(p0.x, p0.y, p1.x, p1.y);
      l4[1] = make_float4(p2.x, p2.y, p3.x, p3.y);
    }
    __syncthreads();
    const int g = t >> 7;
    const int x4 = (t & 127) * 4;
    __half* outA = A1 + (size_t)b * 512 * NN;
    __half* outB = B1 + (size_t)b * 256 * NN;
    for (int jj = 0; jj < 4; ++jj) {
      const int j = jj * 4 + g;
      const int C = isB ? (2 * j) : (c + 2 * j);
      float4 acc = {0.f, 0.f, 0.f, 0.f};
#pragma unroll
      for (int bb = 0; bb < 16; ++bb) {
        int base = (x4 - C * bb * 16) & MASK;  // %4==0: aligned, no wrap split
        float4 v = *(const float4*)&L[bb * 512 + base];
        acc.x += v.x; acc.y += v.y; acc.z += v.z; acc.w += v.w;
      }
      const int orow = isB ? (j * 16 + w) : (C * 16 + w);
      H4 h;
      h.h2[0] = __float22half2_rn(make_float2(acc.x, acc.y));
      h.h2[1] = __float22half2_rn(make_float2(acc.z, acc.w));
      float2* op = (float2*)(isB ? outB : outA);
      op[orow * 128 + (x4 >> 2)] = h.f2;
    }
  }

  bar_signal(&bar[16 + b]);
  bar_wait(&bar[16 + b]);   // phase-2 consumers are the same 48 blocks

  // ====== phase 2: stage 32 -> 512 (H=1), rotated staging, fused out ======
  {
    const bool isB = bx >= 32;
    const int c = isB ? 2 * (bx - 32) : bx;  // stage-32 class
    const __half* in = isB ? (B1 + (size_t)b * 256 * NN + (size_t)(bx - 32) * 16 * NN)
                           : (A1 + (size_t)b * 512 * NN + (size_t)c * 16 * NN);
    float* L = LDS;
    const __half2* i2 = (const __half2*)in;
    for (int it = 0; it < 8; ++it) {
      int flat = it * 512 + t;
      int bb = flat >> 8, p = flat & 255;
      float2 f = __half22float2(i2[bb * 256 + p]);
      int y0 = (2 * p + c * bb) & MASK;     // row bb rotated by c*bb
      L[bb * 512 + y0] = f.x;
      L[bb * 512 + ((y0 + 1) & MASK)] = f.y;
    }
    __syncthreads();
    const int g = t >> 7;
    const int xq = (t & 127) << 2;
    float4 acc[4];
#pragma unroll
    for (int jj = 0; jj < 4; ++jj) acc[jj] = {0.f, 0.f, 0.f, 0.f};
#pragma unroll
    for (int bb = 0; bb < 16; ++bb) {
      const float* row = L + bb * 512;
      int base = (xq - 128 * g * bb) & MASK;  // shift 32*j*bb, j=4g
      const int step = (32 * bb) & MASK;
#pragma unroll
      for (int jj = 0; jj < 4; ++jj) {
        float4 v = *(const float4*)&row[base];  // aligned, wrap-free
        acc[jj].x += v.x; acc[jj].y += v.y; acc[jj].z += v.z; acc[jj].w += v.w;
        base = (base - step) & MASK;
      }
    }
#pragma unroll
    for (int jj = 0; jj < 4; ++jj) {
      const int j = 4 * g + jj;
      const int m = isB ? (512 + (bx - 32) + 16 * j) : (c + 32 * j);
      v4f o1 = {acc[jj].x * SCALE, 0.f, acc[jj].y * SCALE, 0.f};
      v4f o2 = {acc[jj].z * SCALE, 0.f, acc[jj].w * SCALE, 0.f};
      v4f* op = (v4f*)(out + ((size_t)b * MU + m) * NN + xq);
      __builtin_nontemporal_store(o1, op);      // out is never re-read
      __builtin_nontemporal_store(o2, op + 1);
    }
  }
}

// ============ fallback path: 3 separate fp32 kernels (round-3/4) ==========
__global__ __launch_bounds__(256) void k_init(const float* __restrict__ img,
                                              float* __restrict__ A0,
                                              float* __restrict__ B0) {
  const int bx = blockIdx.x, b = blockIdx.y;
  const float* src = img + (size_t)b * NN * NN;
  if (bx < 32) {
    __shared__ float T1[64][65], T2[64][65], T3[64][65];
    const int xt = bx & 7, wt = bx >> 3;
    const int x0 = xt * 64, w0 = wt * 64, x3 = ((xt + 4) & 7) * 64;
    for (int idx = threadIdx.x; idx < 4096; idx += 256) {
      int rr = idx >> 6, cc = idx & 63;
      T1[rr][cc] = src[(x0 + rr) * NN + w0 + cc];
      T2[rr][cc] = src[(x0 + rr) * NN + w0 + 256 + cc];
      T3[rr][cc] = src[(x3 + rr) * NN + w0 + 256 + cc];
    }
    __syncthreads();
    float* dst = A0 + (size_t)b * (512 * NN);
    for (int idx = threadIdx.x; idx < 4096; idx += 256) {
      int wl = idx >> 6, xl = idx & 63;
      float t1 = T1[xl][wl];
      dst[(size_t)(w0 + wl) * NN + x0 + xl]       = t1 + T2[xl][wl];
      dst[(size_t)(256 + w0 + wl) * NN + x0 + xl] = t1 + T3[xl][wl];
    }
  } else {
    const int w0 = (bx - 32) * 32;
    const float4* s4 = (const float4*)src;
    float4* d4 = (float4*)(B0 + (size_t)b * (256 * NN));
    for (int it = 0; it < 16; ++it) {
      int flat = it * 256 + threadIdx.x;
      int row = w0 + (flat >> 7), col = flat & 127;
      float4 u = s4[row * 128 + col], v = s4[(row + 256) * 128 + col];
      u.x += v.x; u.y += v.y; u.z += v.z; u.w += v.w;
      d4[row * 128 + col] = u;
    }
  }
}

__global__ __launch_bounds__(512) void k_pass1(const float* __restrict__ A0,
                                               const float* __restrict__ B0,
                                               float* __restrict__ A1,
                                               float* __restrict__ B1) {
  __shared__ float L[16 * 512];
  const int bx = blockIdx.x, b = blockIdx.y;
  const int t = threadIdx.x;
  const bool isB = bx >= 32;
  const int c = isB ? 0 : (bx >> 4);
  const int w = isB ? (bx - 32) : (bx & 15);
  const float* in = isB ? (B0 + (size_t)b * 256 * NN) : (A0 + (size_t)b * 512 * NN);
  {
    const float4* s4 = (const float4*)in;
    float4* l4 = (float4*)L;
    const int pbase = c * 256 + w;
    for (int it = 0; it < 4; ++it) {
      int flat = it * 512 + t;
      int lrow = flat >> 7, col = flat & 127;
      l4[lrow * 128 + col] = s4[(pbase + 16 * lrow) * 128 + col];
    }
  }
  __syncthreads();
  const int g = t >> 7;
  const int x4 = (t & 127) * 4;
  float* outA = A1 + (size_t)b * 512 * NN;
  float* outB = B1 + (size_t)b * 256 * NN;
  for (int jj = 0; jj < 4; ++jj) {
    const int j = jj * 4 + g;
    const int C = isB ? (2 * j) : (c + 2 * j);
    float4 acc = {0.f, 0.f, 0.f, 0.f};
#pragma unroll
    for (int bb = 0; bb < 16; ++bb) {
      int base = (x4 - C * bb * 16) & MASK;
      float4 v = *(const float4*)&L[bb * 512 + base];
      acc.x += v.x; acc.y += v.y; acc.z += v.z; acc.w += v.w;
    }
    const int orow = isB ? (j * 16 + w) : (C * 16 + w);
    float* op = isB ? outB : outA;
    *(float4*)&op[(size_t)orow * NN + x4] = acc;
  }
}

__global__ __launch_bounds__(512) void k_pass2(const float* __restrict__ A1,
                                               const float* __restrict__ B1,
                                               float2* __restrict__ out) {
  __shared__ float L[16 * 512];
  const int bx = blockIdx.x, b = blockIdx.y;
  const int t = threadIdx.x;
  const bool isB = bx >= 32;
  const int c = isB ? 2 * (bx - 32) : bx;
  const float* in = isB ? (B1 + (size_t)b * 256 * NN + (size_t)(bx - 32) * 16 * NN)
                        : (A1 + (size_t)b * 512 * NN + (size_t)c * 16 * NN);
#pragma unroll
  for (int bb = 0; bb < 16; ++bb) {
    float v = in[bb * 512 + t];
    L[bb * 512 + ((t + c * bb) & MASK)] = v;
  }
  __syncthreads();
  const int g = t >> 7;
  const int xq = (t & 127) << 2;
  float4 acc[4];
#pragma unroll
  for (int jj = 0; jj < 4; ++jj) acc[jj] = {0.f, 0.f, 0.f, 0.f};
#pragma unroll
  for (int bb = 0; bb < 16; ++bb) {
    const float* row = L + bb * 512;
    int base = (xq - 128 * g * bb) & MASK;
    const int step = (32 * bb) & MASK;
#pragma unroll
    for (int jj = 0; jj < 4; ++jj) {
      float4 v = *(const float4*)&row[base];
      acc[jj].x += v.x; acc[jj].y += v.y; acc[jj].z += v.z; acc[jj].w += v.w;
      base = (base - step) & MASK;
    }
  }
#pragma unroll
  for (int jj = 0; jj < 4; ++jj) {
    const int j = 4 * g + jj;
    const int m = isB ? (512 + (bx - 32) + 16 * j) : (c + 32 * j);
    float2* op = out + ((size_t)b * MU + m) * NN + xq;
    float4 a = acc[jj];
    op[0] = {a.x * SCALE, 0.f};
    op[1] = {a.y * SCALE, 0.f};
    op[2] = {a.z * SCALE, 0.f};
    op[3] = {a.w * SCALE, 0.f};
  }
}

extern "C" void kernel_launch(void* const* d_in, const int* in_sizes, int n_in,
                              void* d_out, int out_size, void* d_ws, size_t ws_size,
                              hipStream_t stream) {
  const float* img = (const float*)d_in[0];

  int maxb = 0;
  (void)hipOccupancyMaxActiveBlocksPerMultiprocessor(&maxb, (const void*)drt_fused,
                                                     512, 0);
  const bool can_fuse = (maxb >= 3) && (ws_size >= (size_t)(25165824 + 128));

  if (can_fuse) {
    char* W = (char*)d_ws;
    __half* A0 = (__half*)(W);              // 16 x 512 x 512 fp16
    __half* A1 = (__half*)(W + 8388608);    // 16 x 512 x 512 fp16
    __half* B0 = (__half*)(W + 16777216);   // 16 x 256 x 512 fp16
    __half* B1 = (__half*)(W + 20971520);   // 16 x 256 x 512 fp16
    unsigned* bar = (unsigned*)(W + 25165824);  // 32 per-batch counters
    (void)hipMemsetAsync(bar, 0, 128, stream);  // graph-capturable memset node
    drt_fused<<<dim3(NB), dim3(512), 0, stream>>>(img, (float2*)d_out,
                                                  A0, B0, A1, B1, bar);
  } else if (ws_size >= (size_t)51 * 1024 * 1024) {
    float* W  = (float*)d_ws;
    float* A0 = W;
    float* A1 = W + 4194304;
    float* B0 = W + 8388608;
    float* B1 = W + 10485760;
    k_init <<<dim3(40, 16), dim3(256), 0, stream>>>(img, A0, B0);
    k_pass1<<<dim3(48, 16), dim3(512), 0, stream>>>(A0, B0, A1, B1);
    k_pass2<<<dim3(48, 16), dim3(512), 0, stream>>>(A1, B1, (float2*)d_out);
  }
}